// Round 16
// baseline (184.282 us; speedup 1.0000x reference)
//
#include <hip/hip_runtime.h>

typedef __bf16 bf16;
typedef unsigned int u32;
typedef __attribute__((ext_vector_type(8))) __bf16 bf16x8;
typedef __attribute__((ext_vector_type(4))) __bf16 bf16x4;
typedef __attribute__((ext_vector_type(4))) float floatx4;
typedef __attribute__((ext_vector_type(16))) float floatx16;
typedef __attribute__((ext_vector_type(4))) int int4v;

#define IN_DIM  768
#define ATT_DIM 512
#define NH      8
#define HD      64
#define BATCH   4
#define SEQ     2048
#define M_TOT   (BATCH*SEQ)     // 8192
#define QKV_N   (3*ATT_DIM)     // 1536

// Q scale: 1/sqrt(64) * log2(e)  -> scores exit MFMA in log2 domain
#define QSCALE 0.18033688011112042f

// async 16B global->LDS copy. LDS dest = wave-uniform base + lane*16.
__device__ __forceinline__ void cp16(void* lds, const void* g) {
    __builtin_amdgcn_global_load_lds((const __attribute__((address_space(1))) u32*)g,
                                     (__attribute__((address_space(3))) u32*)lds, 16, 0, 0);
}
// XOR-swizzled accessor for 64-col bf16 tiles staged by cp16:
// 16B chunk c (0..7) of row r lives at slot c ^ (r&7).
__device__ __forceinline__ const bf16* swz(const bf16* b, int row, int chunk) {
    return b + row * 64 + (((chunk) ^ (row & 7)) << 3);
}

// pack two f32 -> one dword of 2 bf16 (low = lo, high = hi)
__device__ __forceinline__ int cvtpk_bf16(float lo, float hi) {
    int r;
    asm("v_cvt_pk_bf16_f32 %0, %1, %2" : "=v"(r) : "v"(lo), "v"(hi));
    return r;
}
// v_permlane32_swap_b32: a.hi-half <-> b.lo-half.
__device__ __forceinline__ void plswap(int& a, int& b) {
    asm("v_permlane32_swap_b32 %0, %1" : "+v"(a), "+v"(b));
}

// ---------------------------------------------------------------------------
// Kernel 0: fp32 -> bf16 conversion of X, W_qkv, W_out
// ---------------------------------------------------------------------------
#define N8_X  (M_TOT * IN_DIM / 8)
#define N8_WQ (QKV_N * IN_DIM / 8)
#define N8_WO (IN_DIM * ATT_DIM / 8)
#define N8_ALL (N8_X + N8_WQ + N8_WO)

__global__ __launch_bounds__(256) void cvt_all(const float* __restrict__ X,
                                               const float* __restrict__ Wq,
                                               const float* __restrict__ Wo,
                                               bf16* __restrict__ Xb,
                                               bf16* __restrict__ Wqb,
                                               bf16* __restrict__ Wob) {
    int i = blockIdx.x * 256 + threadIdx.x;
    const float* s; bf16* d; int off;
    if (i < N8_X)            { s = X;  d = Xb;  off = i; }
    else if (i < N8_X+N8_WQ) { s = Wq; d = Wqb; off = i - N8_X; }
    else                     { s = Wo; d = Wob; off = i - N8_X - N8_WQ; }
    const float4 a = ((const float4*)s)[2*off];
    const float4 b = ((const float4*)s)[2*off+1];
    bf16x8 o = {(bf16)a.x,(bf16)a.y,(bf16)a.z,(bf16)a.w,
                (bf16)b.x,(bf16)b.y,(bf16)b.z,(bf16)b.w};
    ((bf16x8*)d)[off] = o;
}

// ---------------------------------------------------------------------------
// Kernel 1: QKV = Xb * Wqkvb^T (bf16, DMA-staged, BK=64).
// R9/R12/R14-verified: 256-thread 4-wave 64x64 wave tiles, 2-barrier K-loop,
// T1 XCD-chunked swizzle (nwg=768, bijective), block-uniform epilogue
// branches, plain K/VT layouts.
// Q -> [b][h][n][d] (pre-scaled); K -> [b][h][n][d]; V -> [b][h][d][n].
// ---------------------------------------------------------------------------
__global__ __launch_bounds__(256) void qkv_gemm(const bf16* __restrict__ Xb,
                                                const bf16* __restrict__ Wb,
                                                bf16* __restrict__ Q,
                                                bf16* __restrict__ Kv,
                                                bf16* __restrict__ VT) {
    __shared__ __align__(16) char smraw[34816];
    bf16* As = (bf16*)smraw;
    bf16* Bs = (bf16*)(smraw + 16384);

    const int tid  = threadIdx.x;
    // XCD-chunked swizzle: dispatch id -> tile id (96 tiles per XCD chunk)
    const int id  = blockIdx.y * 12 + blockIdx.x;   // gridDim.x == 12
    const int nid = (id & 7) * 96 + (id >> 3);
    const int bm0 = (nid / 12) * 128;
    const int bn0 = (nid % 12) * 128;
    const int wave = tid >> 6, lane = tid & 63;
    const int quad = lane >> 4, l15 = lane & 15;
    const int wm = (wave >> 1) * 64, wn = (wave & 1) * 64;
    const int r8 = lane >> 3, cc = (lane & 7) ^ r8;

    const bf16* ag = Xb + (size_t)(bm0 + wave * 32 + r8) * IN_DIM + cc * 8;
    const bf16* bg = Wb + (size_t)(bn0 + wave * 32 + r8) * IN_DIM + cc * 8;

    floatx4 acc[4][4];
#pragma unroll
    for (int i = 0; i < 4; ++i)
#pragma unroll
        for (int j = 0; j < 4; ++j) acc[i][j] = (floatx4){0.f, 0.f, 0.f, 0.f};

    for (int kt = 0; kt < IN_DIM / 64; ++kt) {
        __syncthreads();
#pragma unroll
        for (int it = 0; it < 4; ++it) {
            cp16(&As[(wave * 32 + it * 8) * 64], ag + it * (8 * IN_DIM) + kt * 64);
            cp16(&Bs[(wave * 32 + it * 8) * 64], bg + it * (8 * IN_DIM) + kt * 64);
        }
        __syncthreads();

        bf16x8 af[2][4], bfr[2][4];
#pragma unroll
        for (int kh = 0; kh < 2; ++kh)
#pragma unroll
            for (int i = 0; i < 4; ++i) {
                af[kh][i]  = *(const bf16x8*)swz(As, wm + i * 16 + l15, kh * 4 + quad);
                bfr[kh][i] = *(const bf16x8*)swz(Bs, wn + i * 16 + l15, kh * 4 + quad);
            }
#pragma unroll
        for (int kh = 0; kh < 2; ++kh)
#pragma unroll
            for (int i = 0; i < 4; ++i)
#pragma unroll
                for (int j = 0; j < 4; ++j)
                    acc[i][j] = __builtin_amdgcn_mfma_f32_16x16x32_bf16(af[kh][i], bfr[kh][j], acc[i][j], 0, 0, 0);
    }

    const int b = bm0 >> 11, nbase = bm0 & 2047;

    if (bn0 < 512) {            // pure-Q block
#pragma unroll
        for (int i = 0; i < 4; ++i)
#pragma unroll
            for (int j = 0; j < 4; ++j)
#pragma unroll
                for (int r = 0; r < 4; ++r) {
                    const int row = bm0 + wm + i * 16 + quad * 4 + r;
                    const int col = bn0 + wn + j * 16 + l15;
                    const int h = col >> 6, d = col & 63;
                    const int n = row & 2047;
                    const size_t idx = (((size_t)((row >> 11) * NH + h)) * SEQ + n) * HD + d;
                    Q[idx] = (bf16)(acc[i][j][r] * QSCALE);
                }
    } else if (bn0 < 1024) {    // pure-K block (plain layout)
#pragma unroll
        for (int i = 0; i < 4; ++i)
#pragma unroll
            for (int j = 0; j < 4; ++j)
#pragma unroll
                for (int r = 0; r < 4; ++r) {
                    const int row = bm0 + wm + i * 16 + quad * 4 + r;
                    const int col = bn0 - 512 + wn + j * 16 + l15;
                    const int h = col >> 6, d = col & 63;
                    const int n = row & 2047;
                    const size_t idx = (((size_t)((row >> 11) * NH + h)) * SEQ + n) * HD + d;
                    Kv[idx] = (bf16)acc[i][j][r];
                }
    } else {
        __syncthreads();
        bf16 (*Ts)[136] = (bf16(*)[136])smraw;
#pragma unroll
        for (int i = 0; i < 4; ++i)
#pragma unroll
            for (int j = 0; j < 4; ++j) {
                bf16x4 pk = {(bf16)acc[i][j][0], (bf16)acc[i][j][1],
                             (bf16)acc[i][j][2], (bf16)acc[i][j][3]};
                *(bf16x4*)&Ts[wn + j * 16 + l15][wm + i * 16 + quad * 4] = pk;
            }
        __syncthreads();
        const int cb = bn0 - 1024;
#pragma unroll
        for (int t2 = 0; t2 < 8; ++t2) {
            const int id2 = tid + t2 * 256;
            const int c = id2 >> 4, nc = (id2 & 15) * 8;
            const int col = cb + c;
            const int h = col >> 6, d = col & 63;
            *(bf16x8*)&VT[(((size_t)(b * NH + h)) * HD + d) * SEQ + nbase + nc] =
                *(const bf16x8*)&Ts[c][nc];
        }
    }
}

// ---------------------------------------------------------------------------
// Kernel 2: flash attention — R16 duplicated-softmax d-split.
// Grid 32 bh x 32 qt (64 q-rows/block), 256 threads; wave = (qh, dh):
// q-group (32 rows) x OUTPUT-D-HALF. Each wave computes the full QK^T +
// softmax for its q-rows (duplicated across the dh pair — deliberate
// redundancy, NO cross-wave communication) but only its 32-wide d-half of
// PV, writing a disjoint quarter of Y. Staging/loop byte-identical to the
// verified R9 attn; 1024 blocks -> 4 blocks/CU = 4 waves/SIMD (vs 2).
// Trades +2x softmax VALU and +1.5x MFMA issue per CU for 2x latency
// hiding on the serial QK->exp2->pack->PV chain (the 7-lever-proven binder).
// ---------------------------------------------------------------------------
__global__ __launch_bounds__(256, 4) void attn(const bf16* __restrict__ Q,
                                               const bf16* __restrict__ K,
                                               const bf16* __restrict__ VT,
                                               bf16* __restrict__ Y) {
    __shared__ bf16 Ks[2][64 * 64];    // 16 KB: 64 keys x 64 d, swz
    __shared__ bf16 VTs[2][64 * 64];   // 16 KB: 64 d x 64 keys, swz

    const int tid  = threadIdx.x;
    const int wave = tid >> 6, lane = tid & 63;
    const int l31  = lane & 31, hi = lane >> 5;
    const int qh   = wave >> 1;        // which 32-q group
    const int dh   = wave & 1;         // which output d-half
    const int bh = blockIdx.x;                 // bh fast dim: same-XCD L2 reuse
    const int q0 = blockIdx.y * 64;
    const bf16* Qg = Q  + (size_t)bh * SEQ * HD;
    const bf16* Kg = K  + (size_t)bh * SEQ * HD;
    const bf16* Vg = VT + (size_t)bh * HD * SEQ;

    // Q fragments (B-operand, col=q=lane&31, k(d)=hi*8+j): 4 chains over D=64
    bf16x8 aq[4];
    {
        const bf16* qrow = Qg + (size_t)(q0 + qh * 32 + l31) * HD;
#pragma unroll
        for (int c = 0; c < 4; ++c)
            aq[c] = *(const bf16x8*)(qrow + c * 16 + hi * 8);
    }

    // staging lanes: 8 rows x 8 chunks, chunk swizzle (row&7); 4 waves x
    // 16 rows = 64 rows (identical to R9).
    const int r8 = lane >> 3, cc8 = (lane & 7) ^ r8;
    const bf16* kgw = Kg + (size_t)(wave * 16 + r8) * HD + cc8 * 8;
    const bf16* vgw = Vg + (size_t)(wave * 16 + r8) * SEQ + cc8 * 8;

    float l = 0.f;
    floatx16 o;                        // only this wave's d-half
#pragma unroll
    for (int i = 0; i < 16; ++i) o[i] = 0.f;

    // prologue: stage tile 0 (64 keys: K 8KB + V 8KB, 4 cp16/thread)
#pragma unroll
    for (int it = 0; it < 2; ++it) {
        cp16(&Ks[0][(wave * 16 + it * 8) * 64], kgw + (size_t)(it * 8) * HD);
        cp16(&VTs[0][(wave * 16 + it * 8) * 64], vgw + (size_t)(it * 8) * SEQ);
    }

    for (int kt = 0; kt < SEQ / 64; ++kt) {
        const int cur = kt & 1;
        __syncthreads();   // drains DMA(kt) (issued one iter ago)
        if (kt < SEQ / 64 - 1) {
#pragma unroll
            for (int it = 0; it < 2; ++it) {
                cp16(&Ks[cur ^ 1][(wave * 16 + it * 8) * 64],
                     kgw + (size_t)((kt + 1) * 64 + it * 8) * HD);
                cp16(&VTs[cur ^ 1][(wave * 16 + it * 8) * 64],
                     vgw + (size_t)(it * 8) * SEQ + (kt + 1) * 64);
            }
        }

#pragma unroll
        for (int kb = 0; kb < 2; ++kb) {
            // S^T = K * Q  (D[row=key][col=q]); K A-operand: row=key=kb*32+l31
            const int krow = kb * 32 + l31;
            floatx16 s;
#pragma unroll
            for (int i = 0; i < 16; ++i) s[i] = 0.f;
#pragma unroll
            for (int c = 0; c < 4; ++c) {
                const bf16x8 kf = *(const bf16x8*)swz(Ks[cur], krow, c * 2 + hi);
                s = __builtin_amdgcn_mfma_f32_32x32x16_bf16(kf, aq[c], s, 0, 0, 0);
            }
            // softmax numerator, fully in-register (duplicated across dh pair)
            float p[16];
#pragma unroll
            for (int i = 0; i < 16; ++i) p[i] = __builtin_amdgcn_exp2f(s[i]);
            {
                const float t0 = (p[0] + p[1]) + (p[2] + p[3]);
                const float t1 = (p[4] + p[5]) + (p[6] + p[7]);
                const float t2 = (p[8] + p[9]) + (p[10] + p[11]);
                const float t3 = (p[12] + p[13]) + (p[14] + p[15]);
                l += (t0 + t1) + (t2 + t3);
            }
            // pack pairs: w[i] = bf16x2 of keys {base+2i, base+2i+1} per hi-half
            int w[8];
#pragma unroll
            for (int i = 0; i < 8; ++i) w[i] = cvtpk_bf16(p[2 * i], p[2 * i + 1]);
            // half-swaps: after these, [w0..w3] = A-frag keys kb*32+0..15,
            // [w4..w7] = A-frag keys kb*32+16..31 (k = hi*8 + j)
            plswap(w[0], w[2]); plswap(w[1], w[3]);
            plswap(w[4], w[6]); plswap(w[5], w[7]);
            const int4v f0i = {w[0], w[1], w[2], w[3]};
            const int4v f1i = {w[4], w[5], w[6], w[7]};
            const bf16x8 f0 = __builtin_bit_cast(bf16x8, f0i);
            const bf16x8 f1 = __builtin_bit_cast(bf16x8, f1i);
            // O += P * V for THIS wave's d-half only: V rows dh*32 + l31
            {
                const int vrow = dh * 32 + l31;
                const bf16x8 v0 = *(const bf16x8*)swz(VTs[cur], vrow, kb * 4 + hi);
                const bf16x8 v1 = *(const bf16x8*)swz(VTs[cur], vrow, kb * 4 + 2 + hi);
                o = __builtin_amdgcn_mfma_f32_32x32x16_bf16(f0, v0, o, 0, 0, 0);
                o = __builtin_amdgcn_mfma_f32_32x32x16_bf16(f1, v1, o, 0, 0, 0);
            }
        }
    }

    // epilogue: finish row sums, distribute 1/l, write this wave's quarter
    l += __shfl_xor(l, 32, 64);
    const float inv = 1.0f / l;
    const int b = bh >> 3, h = bh & 7;
#pragma unroll
    for (int reg = 0; reg < 16; ++reg) {
        const int qr = (reg & 3) + 8 * (reg >> 2) + 4 * hi;
        const float li = __int_as_float(
            __builtin_amdgcn_ds_bpermute(qr << 2, __float_as_int(inv)));
        const int n = q0 + qh * 32 + qr;
        Y[((size_t)(b * SEQ + n)) * ATT_DIM + h * HD + dh * 32 + l31] =
            (bf16)(o[reg] * li);
    }
}

// ---------------------------------------------------------------------------
// Kernel 3: out = Y * Woutb^T + b_out (bf16 DMA-staged, BK=64, fp32 out).
// R9/R12/R14-verified: 2-barrier K-loop + T1 XCD-chunked swizzle (nwg=384,
// bijective; W_out 0.77 MB L2-resident per XCD).
// ---------------------------------------------------------------------------
__global__ __launch_bounds__(256) void out_gemm(const bf16* __restrict__ Yb,
                                                const bf16* __restrict__ Wb,
                                                const float* __restrict__ bias,
                                                float* __restrict__ out) {
    __shared__ __align__(16) bf16 As[128 * 64];
    __shared__ __align__(16) bf16 Bs[128 * 64];

    const int tid  = threadIdx.x;
    const int id  = blockIdx.y * 6 + blockIdx.x;    // gridDim.x == 6
    const int nid = (id & 7) * 48 + (id >> 3);
    const int bm0 = (nid / 6) * 128;
    const int bn0 = (nid % 6) * 128;
    const int wave = tid >> 6, lane = tid & 63;
    const int quad = lane >> 4, l15 = lane & 15;
    const int wm = (wave >> 1) * 64, wn = (wave & 1) * 64;
    const int r8 = lane >> 3, cc = (lane & 7) ^ r8;

    const bf16* ag = Yb + (size_t)(bm0 + wave * 32 + r8) * ATT_DIM + cc * 8;
    const bf16* bg = Wb + (size_t)(bn0 + wave * 32 + r8) * ATT_DIM + cc * 8;

    floatx4 acc[4][4];
#pragma unroll
    for (int i = 0; i < 4; ++i)
#pragma unroll
        for (int j = 0; j < 4; ++j) acc[i][j] = (floatx4){0.f, 0.f, 0.f, 0.f};

    for (int kt = 0; kt < ATT_DIM / 64; ++kt) {
        __syncthreads();
#pragma unroll
        for (int it = 0; it < 4; ++it) {
            cp16(&As[(wave * 32 + it * 8) * 64], ag + it * (8 * ATT_DIM) + kt * 64);
            cp16(&Bs[(wave * 32 + it * 8) * 64], bg + it * (8 * ATT_DIM) + kt * 64);
        }
        __syncthreads();

        bf16x8 af[2][4], bfr[2][4];
#pragma unroll
        for (int kh = 0; kh < 2; ++kh)
#pragma unroll
            for (int i = 0; i < 4; ++i) {
                af[kh][i]  = *(const bf16x8*)swz(As, wm + i * 16 + l15, kh * 4 + quad);
                bfr[kh][i] = *(const bf16x8*)swz(Bs, wn + i * 16 + l15, kh * 4 + quad);
            }
#pragma unroll
        for (int kh = 0; kh < 2; ++kh)
#pragma unroll
            for (int i = 0; i < 4; ++i)
#pragma unroll
                for (int j = 0; j < 4; ++j)
                    acc[i][j] = __builtin_amdgcn_mfma_f32_16x16x32_bf16(af[kh][i], bfr[kh][j], acc[i][j], 0, 0, 0);
    }

#pragma unroll
    for (int i = 0; i < 4; ++i)
#pragma unroll
        for (int j = 0; j < 4; ++j)
#pragma unroll
            for (int r = 0; r < 4; ++r) {
                const int row = bm0 + wm + i * 16 + quad * 4 + r;
                const int col = bn0 + wn + j * 16 + l15;
                out[(size_t)row * IN_DIM + col] = acc[i][j][r] + bias[col];
            }
}

// ---------------------------------------------------------------------------
extern "C" void kernel_launch(void* const* d_in, const int* in_sizes, int n_in,
                              void* d_out, int out_size, void* d_ws, size_t ws_size,
                              hipStream_t stream) {
    const float* X    = (const float*)d_in[0];
    const float* Wqkv = (const float*)d_in[1];
    const float* Wout = (const float*)d_in[2];
    const float* bout = (const float*)d_in[3];
    float* out = (float*)d_out;

    char* ws = (char*)d_ws;
    size_t off = 0;
    bf16* Xb  = (bf16*)(ws + off); off += (size_t)M_TOT * IN_DIM * 2;
    bf16* Wqb = (bf16*)(ws + off); off += (size_t)QKV_N * IN_DIM * 2;
    bf16* Wob = (bf16*)(ws + off); off += (size_t)IN_DIM * ATT_DIM * 2;
    const size_t T = (size_t)BATCH * NH * SEQ * HD * 2;
    bf16* Q  = (bf16*)(ws + off); off += T;
    bf16* K  = (bf16*)(ws + off); off += T;
    bf16* VT = (bf16*)(ws + off); off += T;
    bf16* Y  = (bf16*)(ws + off); off += T;

    cvt_all<<<N8_ALL / 256, 256, 0, stream>>>(X, Wqkv, Wout, Xb, Wqb, Wob);
    qkv_gemm<<<dim3(QKV_N / 128, M_TOT / 128), 256, 0, stream>>>(Xb, Wqb, Q, K, VT);
    attn<<<dim3(BATCH * NH, SEQ / 64), 256, 0, stream>>>(Q, K, VT, Y);
    out_gemm<<<dim3(IN_DIM / 128, M_TOT / 128), 256, 0, stream>>>(Y, Wob, bout, out);
}

// Round 17
// 157.632 us; speedup vs baseline: 1.1691x; 1.1691x over previous
//
#include <hip/hip_runtime.h>

typedef __bf16 bf16;
typedef unsigned int u32;
typedef __attribute__((ext_vector_type(8))) __bf16 bf16x8;
typedef __attribute__((ext_vector_type(4))) __bf16 bf16x4;
typedef __attribute__((ext_vector_type(4))) float floatx4;
typedef __attribute__((ext_vector_type(16))) float floatx16;
typedef __attribute__((ext_vector_type(4))) int int4v;

#define IN_DIM  768
#define ATT_DIM 512
#define NH      8
#define HD      64
#define BATCH   4
#define SEQ     2048
#define M_TOT   (BATCH*SEQ)     // 8192
#define QKV_N   (3*ATT_DIM)     // 1536

// Q scale: 1/sqrt(64) * log2(e)  -> scores exit MFMA in log2 domain
#define QSCALE 0.18033688011112042f

// async 16B global->LDS copy. LDS dest = wave-uniform base + lane*16.
__device__ __forceinline__ void cp16(void* lds, const void* g) {
    __builtin_amdgcn_global_load_lds((const __attribute__((address_space(1))) u32*)g,
                                     (__attribute__((address_space(3))) u32*)lds, 16, 0, 0);
}
// XOR-swizzled accessor for 64-col bf16 tiles staged by cp16:
// 16B chunk c (0..7) of row r lives at slot c ^ (r&7).
__device__ __forceinline__ const bf16* swz(const bf16* b, int row, int chunk) {
    return b + row * 64 + (((chunk) ^ (row & 7)) << 3);
}

// pack two f32 -> one dword of 2 bf16 (low = lo, high = hi)
__device__ __forceinline__ int cvtpk_bf16(float lo, float hi) {
    int r;
    asm("v_cvt_pk_bf16_f32 %0, %1, %2" : "=v"(r) : "v"(lo), "v"(hi));
    return r;
}
// v_permlane32_swap_b32: a.hi-half <-> b.lo-half.
__device__ __forceinline__ void plswap(int& a, int& b) {
    asm("v_permlane32_swap_b32 %0, %1" : "+v"(a), "+v"(b));
}

// ---------------------------------------------------------------------------
// Kernel 0: fp32 -> bf16 conversion of X, W_qkv, W_out
// ---------------------------------------------------------------------------
#define N8_X  (M_TOT * IN_DIM / 8)
#define N8_WQ (QKV_N * IN_DIM / 8)
#define N8_WO (IN_DIM * ATT_DIM / 8)
#define N8_ALL (N8_X + N8_WQ + N8_WO)

__global__ __launch_bounds__(256) void cvt_all(const float* __restrict__ X,
                                               const float* __restrict__ Wq,
                                               const float* __restrict__ Wo,
                                               bf16* __restrict__ Xb,
                                               bf16* __restrict__ Wqb,
                                               bf16* __restrict__ Wob) {
    int i = blockIdx.x * 256 + threadIdx.x;
    const float* s; bf16* d; int off;
    if (i < N8_X)            { s = X;  d = Xb;  off = i; }
    else if (i < N8_X+N8_WQ) { s = Wq; d = Wqb; off = i - N8_X; }
    else                     { s = Wo; d = Wob; off = i - N8_X - N8_WQ; }
    const float4 a = ((const float4*)s)[2*off];
    const float4 b = ((const float4*)s)[2*off+1];
    bf16x8 o = {(bf16)a.x,(bf16)a.y,(bf16)a.z,(bf16)a.w,
                (bf16)b.x,(bf16)b.y,(bf16)b.z,(bf16)b.w};
    ((bf16x8*)d)[off] = o;
}

// ---------------------------------------------------------------------------
// Kernel 1: QKV = Xb * Wqkvb^T (bf16, DMA-staged, BK=64).
// Final (R9/R12/R14-verified, best-measured): 256-thread 4-wave 64x64 wave
// tiles, 2-barrier K-loop, T1 XCD-chunked swizzle (nwg=768, bijective:
// each XCD gets 8 contiguous M-panels x all 12 N-blocks; B L2-resident per
// XCD), block-uniform epilogue branches, plain K/VT layouts.
// Q -> [b][h][n][d] (pre-scaled); K -> [b][h][n][d]; V -> [b][h][d][n].
// ---------------------------------------------------------------------------
__global__ __launch_bounds__(256) void qkv_gemm(const bf16* __restrict__ Xb,
                                                const bf16* __restrict__ Wb,
                                                bf16* __restrict__ Q,
                                                bf16* __restrict__ Kv,
                                                bf16* __restrict__ VT) {
    __shared__ __align__(16) char smraw[34816];
    bf16* As = (bf16*)smraw;
    bf16* Bs = (bf16*)(smraw + 16384);

    const int tid  = threadIdx.x;
    // XCD-chunked swizzle: dispatch id -> tile id (96 tiles per XCD chunk)
    const int id  = blockIdx.y * 12 + blockIdx.x;   // gridDim.x == 12
    const int nid = (id & 7) * 96 + (id >> 3);
    const int bm0 = (nid / 12) * 128;
    const int bn0 = (nid % 12) * 128;
    const int wave = tid >> 6, lane = tid & 63;
    const int quad = lane >> 4, l15 = lane & 15;
    const int wm = (wave >> 1) * 64, wn = (wave & 1) * 64;
    const int r8 = lane >> 3, cc = (lane & 7) ^ r8;

    const bf16* ag = Xb + (size_t)(bm0 + wave * 32 + r8) * IN_DIM + cc * 8;
    const bf16* bg = Wb + (size_t)(bn0 + wave * 32 + r8) * IN_DIM + cc * 8;

    floatx4 acc[4][4];
#pragma unroll
    for (int i = 0; i < 4; ++i)
#pragma unroll
        for (int j = 0; j < 4; ++j) acc[i][j] = (floatx4){0.f, 0.f, 0.f, 0.f};

    for (int kt = 0; kt < IN_DIM / 64; ++kt) {
        __syncthreads();
#pragma unroll
        for (int it = 0; it < 4; ++it) {
            cp16(&As[(wave * 32 + it * 8) * 64], ag + it * (8 * IN_DIM) + kt * 64);
            cp16(&Bs[(wave * 32 + it * 8) * 64], bg + it * (8 * IN_DIM) + kt * 64);
        }
        __syncthreads();

        bf16x8 af[2][4], bfr[2][4];
#pragma unroll
        for (int kh = 0; kh < 2; ++kh)
#pragma unroll
            for (int i = 0; i < 4; ++i) {
                af[kh][i]  = *(const bf16x8*)swz(As, wm + i * 16 + l15, kh * 4 + quad);
                bfr[kh][i] = *(const bf16x8*)swz(Bs, wn + i * 16 + l15, kh * 4 + quad);
            }
#pragma unroll
        for (int kh = 0; kh < 2; ++kh)
#pragma unroll
            for (int i = 0; i < 4; ++i)
#pragma unroll
                for (int j = 0; j < 4; ++j)
                    acc[i][j] = __builtin_amdgcn_mfma_f32_16x16x32_bf16(af[kh][i], bfr[kh][j], acc[i][j], 0, 0, 0);
    }

    const int b = bm0 >> 11, nbase = bm0 & 2047;

    if (bn0 < 512) {            // pure-Q block
#pragma unroll
        for (int i = 0; i < 4; ++i)
#pragma unroll
            for (int j = 0; j < 4; ++j)
#pragma unroll
                for (int r = 0; r < 4; ++r) {
                    const int row = bm0 + wm + i * 16 + quad * 4 + r;
                    const int col = bn0 + wn + j * 16 + l15;
                    const int h = col >> 6, d = col & 63;
                    const int n = row & 2047;
                    const size_t idx = (((size_t)((row >> 11) * NH + h)) * SEQ + n) * HD + d;
                    Q[idx] = (bf16)(acc[i][j][r] * QSCALE);
                }
    } else if (bn0 < 1024) {    // pure-K block (plain layout)
#pragma unroll
        for (int i = 0; i < 4; ++i)
#pragma unroll
            for (int j = 0; j < 4; ++j)
#pragma unroll
                for (int r = 0; r < 4; ++r) {
                    const int row = bm0 + wm + i * 16 + quad * 4 + r;
                    const int col = bn0 - 512 + wn + j * 16 + l15;
                    const int h = col >> 6, d = col & 63;
                    const int n = row & 2047;
                    const size_t idx = (((size_t)((row >> 11) * NH + h)) * SEQ + n) * HD + d;
                    Kv[idx] = (bf16)acc[i][j][r];
                }
    } else {
        __syncthreads();
        bf16 (*Ts)[136] = (bf16(*)[136])smraw;
#pragma unroll
        for (int i = 0; i < 4; ++i)
#pragma unroll
            for (int j = 0; j < 4; ++j) {
                bf16x4 pk = {(bf16)acc[i][j][0], (bf16)acc[i][j][1],
                             (bf16)acc[i][j][2], (bf16)acc[i][j][3]};
                *(bf16x4*)&Ts[wn + j * 16 + l15][wm + i * 16 + quad * 4] = pk;
            }
        __syncthreads();
        const int cb = bn0 - 1024;
#pragma unroll
        for (int t2 = 0; t2 < 8; ++t2) {
            const int id2 = tid + t2 * 256;
            const int c = id2 >> 4, nc = (id2 & 15) * 8;
            const int col = cb + c;
            const int h = col >> 6, d = col & 63;
            *(bf16x8*)&VT[(((size_t)(b * NH + h)) * HD + d) * SEQ + nbase + nc] =
                *(const bf16x8*)&Ts[c][nc];
        }
    }
}

// ---------------------------------------------------------------------------
// Kernel 2: flash attention — final (R9/R12/R14-verified, 48.4-51.3 us).
// 512 blocks (32 bh x 16 qt), 4 waves x 32 q-rows, KVBLK=64 dbuf, b128 swz
// fragment reads, single s/o accumulators, no setprio, direct-Y epilogue.
// Session evidence — EIGHT falsified levers on this structure: kb-split
// occupancy (race in exchange), split-K via HBM (traffic-bound), ILP
// accumulator splits (VALU path), 2x-b64 reads (issue count), setprio
// (lockstep), bank-conflict elimination (R13: 4.2M->0, zero time change),
// KVBLK=128 barrier halving (null), duplicated-softmax d-split (R16:
// occupancy 18->31 but work x2 => +48%). Conclusion: work-bound on the
// combined MFMA+VALU+LDS issue stream; the only unexplored path is a full
// 8-phase counted-vmcnt restructure (new sync template, out of budget).
// ---------------------------------------------------------------------------
__global__ __launch_bounds__(256, 4) void attn(const bf16* __restrict__ Q,
                                               const bf16* __restrict__ K,
                                               const bf16* __restrict__ VT,
                                               bf16* __restrict__ Y) {
    __shared__ bf16 Ks[2][64 * 64];    // 16 KB: 64 keys x 64 d, swz
    __shared__ bf16 VTs[2][64 * 64];   // 16 KB: 64 d x 64 keys, swz

    const int tid  = threadIdx.x;
    const int wave = tid >> 6, lane = tid & 63;
    const int l31  = lane & 31, hi = lane >> 5;
    const int bh = blockIdx.x;                 // bh fast dim: same-XCD L2 reuse
    const int q0 = blockIdx.y * 128;
    const bf16* Qg = Q  + (size_t)bh * SEQ * HD;
    const bf16* Kg = K  + (size_t)bh * SEQ * HD;
    const bf16* Vg = VT + (size_t)bh * HD * SEQ;

    // Q fragments (B-operand, col=q=lane&31, k(d)=hi*8+j): 4 chains over D=64
    bf16x8 aq[4];
    {
        const bf16* qrow = Qg + (size_t)(q0 + wave * 32 + l31) * HD;
#pragma unroll
        for (int c = 0; c < 4; ++c)
            aq[c] = *(const bf16x8*)(qrow + c * 16 + hi * 8);
    }

    // staging lanes: 8 rows x 8 chunks, chunk swizzle (row&7)
    const int r8 = lane >> 3, cc8 = (lane & 7) ^ r8;
    const bf16* kgw = Kg + (size_t)(wave * 16 + r8) * HD + cc8 * 8;
    const bf16* vgw = Vg + (size_t)(wave * 16 + r8) * SEQ + cc8 * 8;

    float l = 0.f;
    floatx16 o[2];
#pragma unroll
    for (int i = 0; i < 16; ++i) { o[0][i] = 0.f; o[1][i] = 0.f; }

    // prologue: stage tile 0 (64 keys: K 8KB + V 8KB, 4 cp16/thread)
#pragma unroll
    for (int it = 0; it < 2; ++it) {
        cp16(&Ks[0][(wave * 16 + it * 8) * 64], kgw + (size_t)(it * 8) * HD);
        cp16(&VTs[0][(wave * 16 + it * 8) * 64], vgw + (size_t)(it * 8) * SEQ);
    }

    for (int kt = 0; kt < SEQ / 64; ++kt) {
        const int cur = kt & 1;
        __syncthreads();   // drains DMA(kt) (issued one iter ago)
        if (kt < SEQ / 64 - 1) {
#pragma unroll
            for (int it = 0; it < 2; ++it) {
                cp16(&Ks[cur ^ 1][(wave * 16 + it * 8) * 64],
                     kgw + (size_t)((kt + 1) * 64 + it * 8) * HD);
                cp16(&VTs[cur ^ 1][(wave * 16 + it * 8) * 64],
                     vgw + (size_t)(it * 8) * SEQ + (kt + 1) * 64);
            }
        }

#pragma unroll
        for (int kb = 0; kb < 2; ++kb) {
            // S^T = K * Q  (D[row=key][col=q]); K A-operand: row=key=kb*32+l31
            const int krow = kb * 32 + l31;
            floatx16 s;
#pragma unroll
            for (int i = 0; i < 16; ++i) s[i] = 0.f;
#pragma unroll
            for (int c = 0; c < 4; ++c) {
                const bf16x8 kf = *(const bf16x8*)swz(Ks[cur], krow, c * 2 + hi);
                s = __builtin_amdgcn_mfma_f32_32x32x16_bf16(kf, aq[c], s, 0, 0, 0);
            }
            // softmax numerator, fully in-register. lane q = l31,
            // keys(reg) = kb*32 + (reg&3) + 8*(reg>>2) + 4*hi
            float p[16];
#pragma unroll
            for (int i = 0; i < 16; ++i) p[i] = __builtin_amdgcn_exp2f(s[i]);
            {
                const float t0 = (p[0] + p[1]) + (p[2] + p[3]);
                const float t1 = (p[4] + p[5]) + (p[6] + p[7]);
                const float t2 = (p[8] + p[9]) + (p[10] + p[11]);
                const float t3 = (p[12] + p[13]) + (p[14] + p[15]);
                l += (t0 + t1) + (t2 + t3);
            }
            // pack pairs: w[i] = bf16x2 of keys {base+2i, base+2i+1} per hi-half
            int w[8];
#pragma unroll
            for (int i = 0; i < 8; ++i) w[i] = cvtpk_bf16(p[2 * i], p[2 * i + 1]);
            // half-swaps: after these, [w0..w3] = A-frag keys kb*32+0..15,
            // [w4..w7] = A-frag keys kb*32+16..31 (k = hi*8 + j)
            plswap(w[0], w[2]); plswap(w[1], w[3]);
            plswap(w[4], w[6]); plswap(w[5], w[7]);
            const int4v f0i = {w[0], w[1], w[2], w[3]};
            const int4v f1i = {w[4], w[5], w[6], w[7]};
            const bf16x8 f0 = __builtin_bit_cast(bf16x8, f0i);
            const bf16x8 f1 = __builtin_bit_cast(bf16x8, f1i);
            // O += P * V ; V B-operand from VTs: col=d=db*32+l31, keys chunked
#pragma unroll
            for (int db = 0; db < 2; ++db) {
                const int vrow = db * 32 + l31;
                const bf16x8 v0 = *(const bf16x8*)swz(VTs[cur], vrow, kb * 4 + hi);
                const bf16x8 v1 = *(const bf16x8*)swz(VTs[cur], vrow, kb * 4 + 2 + hi);
                o[db] = __builtin_amdgcn_mfma_f32_32x32x16_bf16(f0, v0, o[db], 0, 0, 0);
                o[db] = __builtin_amdgcn_mfma_f32_32x32x16_bf16(f1, v1, o[db], 0, 0, 0);
            }
        }
    }

    // epilogue: finish row sums, distribute 1/l, write Y
    l += __shfl_xor(l, 32, 64);
    const float inv = 1.0f / l;
    const int b = bh >> 3, h = bh & 7;
#pragma unroll
    for (int reg = 0; reg < 16; ++reg) {
        const int qr = (reg & 3) + 8 * (reg >> 2) + 4 * hi;
        const float li = __int_as_float(
            __builtin_amdgcn_ds_bpermute(qr << 2, __float_as_int(inv)));
        const int n = q0 + wave * 32 + qr;
        bf16* yrow = Y + ((size_t)(b * SEQ + n)) * ATT_DIM + h * HD + l31;
        yrow[0]  = (bf16)(o[0][reg] * li);
        yrow[32] = (bf16)(o[1][reg] * li);
    }
}

// ---------------------------------------------------------------------------
// Kernel 3: out = Y * Woutb^T + b_out (bf16 DMA-staged, BK=64, fp32 out).
// Final (R9/R12/R14-verified): 2-barrier K-loop + T1 XCD-chunked swizzle
// (nwg=384, bijective; W_out 0.77 MB L2-resident per XCD).
// ---------------------------------------------------------------------------
__global__ __launch_bounds__(256) void out_gemm(const bf16* __restrict__ Yb,
                                                const bf16* __restrict__ Wb,
                                                const float* __restrict__ bias,
                                                float* __restrict__ out) {
    __shared__ __align__(16) bf16 As[128 * 64];
    __shared__ __align__(16) bf16 Bs[128 * 64];

    const int tid  = threadIdx.x;
    const int id  = blockIdx.y * 6 + blockIdx.x;    // gridDim.x == 6
    const int nid = (id & 7) * 48 + (id >> 3);
    const int bm0 = (nid / 6) * 128;
    const int bn0 = (nid % 6) * 128;
    const int wave = tid >> 6, lane = tid & 63;
    const int quad = lane >> 4, l15 = lane & 15;
    const int wm = (wave >> 1) * 64, wn = (wave & 1) * 64;
    const int r8 = lane >> 3, cc = (lane & 7) ^ r8;

    const bf16* ag = Yb + (size_t)(bm0 + wave * 32 + r8) * ATT_DIM + cc * 8;
    const bf16* bg = Wb + (size_t)(bn0 + wave * 32 + r8) * ATT_DIM + cc * 8;

    floatx4 acc[4][4];
#pragma unroll
    for (int i = 0; i < 4; ++i)
#pragma unroll
        for (int j = 0; j < 4; ++j) acc[i][j] = (floatx4){0.f, 0.f, 0.f, 0.f};

    for (int kt = 0; kt < ATT_DIM / 64; ++kt) {
        __syncthreads();
#pragma unroll
        for (int it = 0; it < 4; ++it) {
            cp16(&As[(wave * 32 + it * 8) * 64], ag + it * (8 * ATT_DIM) + kt * 64);
            cp16(&Bs[(wave * 32 + it * 8) * 64], bg + it * (8 * ATT_DIM) + kt * 64);
        }
        __syncthreads();

        bf16x8 af[2][4], bfr[2][4];
#pragma unroll
        for (int kh = 0; kh < 2; ++kh)
#pragma unroll
            for (int i = 0; i < 4; ++i) {
                af[kh][i]  = *(const bf16x8*)swz(As, wm + i * 16 + l15, kh * 4 + quad);
                bfr[kh][i] = *(const bf16x8*)swz(Bs, wn + i * 16 + l15, kh * 4 + quad);
            }
#pragma unroll
        for (int kh = 0; kh < 2; ++kh)
#pragma unroll
            for (int i = 0; i < 4; ++i)
#pragma unroll
                for (int j = 0; j < 4; ++j)
                    acc[i][j] = __builtin_amdgcn_mfma_f32_16x16x32_bf16(af[kh][i], bfr[kh][j], acc[i][j], 0, 0, 0);
    }

#pragma unroll
    for (int i = 0; i < 4; ++i)
#pragma unroll
        for (int j = 0; j < 4; ++j)
#pragma unroll
            for (int r = 0; r < 4; ++r) {
                const int row = bm0 + wm + i * 16 + quad * 4 + r;
                const int col = bn0 + wn + j * 16 + l15;
                out[(size_t)row * IN_DIM + col] = acc[i][j][r] + bias[col];
            }
}

// ---------------------------------------------------------------------------
extern "C" void kernel_launch(void* const* d_in, const int* in_sizes, int n_in,
                              void* d_out, int out_size, void* d_ws, size_t ws_size,
                              hipStream_t stream) {
    const float* X    = (const float*)d_in[0];
    const float* Wqkv = (const float*)d_in[1];
    const float* Wout = (const float*)d_in[2];
    const float* bout = (const float*)d_in[3];
    float* out = (float*)d_out;

    char* ws = (char*)d_ws;
    size_t off = 0;
    bf16* Xb  = (bf16*)(ws + off); off += (size_t)M_TOT * IN_DIM * 2;
    bf16* Wqb = (bf16*)(ws + off); off += (size_t)QKV_N * IN_DIM * 2;
    bf16* Wob = (bf16*)(ws + off); off += (size_t)IN_DIM * ATT_DIM * 2;
    const size_t T = (size_t)BATCH * NH * SEQ * HD * 2;
    bf16* Q  = (bf16*)(ws + off); off += T;
    bf16* K  = (bf16*)(ws + off); off += T;
    bf16* VT = (bf16*)(ws + off); off += T;
    bf16* Y  = (bf16*)(ws + off); off += T;

    cvt_all<<<N8_ALL / 256, 256, 0, stream>>>(X, Wqkv, Wout, Xb, Wqb, Wob);
    qkv_gemm<<<dim3(QKV_N / 128, M_TOT / 128), 256, 0, stream>>>(Xb, Wqb, Q, K, VT);
    attn<<<dim3(BATCH * NH, SEQ / 128), 256, 0, stream>>>(Q, K, VT, Y);
    out_gemm<<<dim3(IN_DIM / 128, M_TOT / 128), 256, 0, stream>>>(Y, Wob, bout, out);
}